// Round 3
// baseline (563.161 us; speedup 1.0000x reference)
//
#include <hip/hip_runtime.h>

// Unpooling (2x2, stride 2, pad 0), B=32 C=64 H=W=112 -> Ho=Wo=224.
//
// DTYPES: feature_map fp32, switches int32, out fp32.
//
// Scatter inverted to gather/expand: input element (hi,wi) owns the disjoint
// 2x2 output block at (2hi, 2wi); switches in [0,4) picks the cell
// (s=0:(0,0) s=1:(0,1) s=2:(1,0) s=3:(1,1)), other 3 cells are zero.
// Every output element written exactly once -> no atomics, no zero-init.
//
// Round-2: 16B loads vs 8B was NULL (526.5 -> 540.2, within fill variance).
// Round-3: nontemporal failed to COMPILE on HIP_vector_type (float4/int4) --
// the builtin needs scalar or clang ext_vector pointers. This round: same
// nt-policy theory, expressed via ext_vector_type(4) (layout-identical).
// All three streams are zero-reuse streaming through a 32 MB L2; nt is the
// last lever that could raise effective BW without changing traffic.

#define BB 32
#define CC 64
#define HH 112
#define WW 112
#define HO 224
#define WO 224

typedef float f32x4 __attribute__((ext_vector_type(4)));
typedef int   i32x4 __attribute__((ext_vector_type(4)));

__global__ __launch_bounds__(256) void unpool_kernel(
    const float* __restrict__ fm,
    const int*   __restrict__ sw,
    float*       __restrict__ out)
{
    const int tid = blockIdx.x * blockDim.x + threadIdx.x;
    // total threads = B*C*H*(W/4) = 6,422,528 ; grid sized exactly, no bounds check
    const int chunk = tid % (WW / 4);        // 4-wide chunk within the input row
    const int rowid = tid / (WW / 4);        // global input row index
    const int hi    = rowid % HH;
    const int plane = rowid / HH;            // b*C + c

    const int in_idx = tid * 4;              // flat input element index (contiguous)
    const f32x4 f = __builtin_nontemporal_load(
        reinterpret_cast<const f32x4*>(fm + in_idx));
    const i32x4 s = __builtin_nontemporal_load(
        reinterpret_cast<const i32x4*>(sw + in_idx));

    // s: 0 -> (dr=0,dc=0), 1 -> (0,1), 2 -> (1,0), 3 -> (1,1)
    f32x4 e0, e1, o0, o1;
    e0.x = (s.x == 0) ? f.x : 0.0f;          // out row 2hi, cols 8c..8c+3
    e0.y = (s.x == 1) ? f.x : 0.0f;
    e0.z = (s.y == 0) ? f.y : 0.0f;
    e0.w = (s.y == 1) ? f.y : 0.0f;
    e1.x = (s.z == 0) ? f.z : 0.0f;          // out row 2hi, cols 8c+4..8c+7
    e1.y = (s.z == 1) ? f.z : 0.0f;
    e1.z = (s.w == 0) ? f.w : 0.0f;
    e1.w = (s.w == 1) ? f.w : 0.0f;
    o0.x = (s.x == 2) ? f.x : 0.0f;          // out row 2hi+1, cols 8c..8c+3
    o0.y = (s.x == 3) ? f.x : 0.0f;
    o0.z = (s.y == 2) ? f.y : 0.0f;
    o0.w = (s.y == 3) ? f.y : 0.0f;
    o1.x = (s.z == 2) ? f.z : 0.0f;          // out row 2hi+1, cols 8c+4..8c+7
    o1.y = (s.z == 3) ? f.z : 0.0f;
    o1.z = (s.w == 2) ? f.w : 0.0f;
    o1.w = (s.w == 3) ? f.w : 0.0f;

    // all 16B aligned: plane stride 200,704 B, row pitch 896 B, chunk step 32 B
    const int out_base = plane * (HO * WO) + (hi * 2) * WO + chunk * 8;
    __builtin_nontemporal_store(e0, reinterpret_cast<f32x4*>(out + out_base));
    __builtin_nontemporal_store(e1, reinterpret_cast<f32x4*>(out + out_base + 4));
    __builtin_nontemporal_store(o0, reinterpret_cast<f32x4*>(out + out_base + WO));
    __builtin_nontemporal_store(o1, reinterpret_cast<f32x4*>(out + out_base + WO + 4));
}

extern "C" void kernel_launch(void* const* d_in, const int* in_sizes, int n_in,
                              void* d_out, int out_size, void* d_ws, size_t ws_size,
                              hipStream_t stream) {
    const float* fm = (const float*)d_in[0];   // fp32 feature_map
    const int*   sw = (const int*)d_in[1];     // int32 switches
    float*       out = (float*)d_out;          // fp32 output

    const int total_threads = BB * CC * HH * (WW / 4);   // 6,422,528
    const int block = 256;
    const int grid  = total_threads / block;             // 25,088 exactly
    unpool_kernel<<<grid, block, 0, stream>>>(fm, sw, out);
}

// Round 4
// 533.292 us; speedup vs baseline: 1.0560x; 1.0560x over previous
//
#include <hip/hip_runtime.h>

// Unpooling (2x2, stride 2, pad 0), B=32 C=64 H=W=112 -> Ho=Wo=224.
//
// DTYPES: feature_map fp32, switches int32, out fp32.
//
// Scatter inverted to gather/expand: input element (hi,wi) owns the disjoint
// 2x2 output block at (2hi, 2wi); switches in [0,4) picks the cell
// (s=0:(0,0) s=1:(0,1) s=2:(1,0) s=3:(1,1)), other 3 cells are zero.
// Every output element written exactly once -> no atomics, no zero-init.
//
// SESSION CONCLUSION (rounds 0-3): this variant is the keeper.
//   r0 8B-loads           : 526.5 us   <- best (prev session: 532.3)
//   r1 16B-loads          : 540.2 us   (2x fewer waves -- NULL)
//   r3 16B-nontemporal    : 563.2 us   (nt policy -- no gain, slight regression)
// Spread tracks harness poison-fill variance (256-266 us run-to-run).
// Structural constraint: obligatory traffic 616.6 MB (205.5 R + 411 W),
// ~98 us at 6.3 TB/s; the rest of dur_us is fixed harness work (1.644 GB
// poison fill at 77-80% HBM peak + input restore). No kernel edit moves it.

#define BB 32
#define CC 64
#define HH 112
#define WW 112
#define HO 224
#define WO 224

__global__ __launch_bounds__(256) void unpool_kernel(
    const float* __restrict__ fm,
    const int*   __restrict__ sw,
    float*       __restrict__ out)
{
    const int tid = blockIdx.x * blockDim.x + threadIdx.x;
    // total threads = B*C*H*(W/2) = 12,845,056 ; grid sized exactly, no bounds check
    const int chunk = tid % (WW / 2);        // 2-wide chunk within the input row
    const int rowid = tid / (WW / 2);        // global input row index
    const int hi    = rowid % HH;
    const int plane = rowid / HH;            // b*C + c

    const int in_idx = tid * 2;              // flat input element index (contiguous)
    const float2 f = *(const float2*)(fm + in_idx);
    const int2   s = *(const int2*)(sw + in_idx);

    // s: 0 -> (dr=0,dc=0), 1 -> (0,1), 2 -> (1,0), 3 -> (1,1)
    float4 o_even, o_odd;
    o_even.x = (s.x == 0) ? f.x : 0.0f;
    o_even.y = (s.x == 1) ? f.x : 0.0f;
    o_even.z = (s.y == 0) ? f.y : 0.0f;
    o_even.w = (s.y == 1) ? f.y : 0.0f;
    o_odd.x  = (s.x == 2) ? f.x : 0.0f;
    o_odd.y  = (s.x == 3) ? f.x : 0.0f;
    o_odd.z  = (s.y == 2) ? f.y : 0.0f;
    o_odd.w  = (s.y == 3) ? f.y : 0.0f;

    const int out_base = plane * (HO * WO) + (hi * 2) * WO + chunk * 4;  // < 2^31
    *(float4*)(out + out_base)      = o_even;  // row 2*hi,   16B aligned
    *(float4*)(out + out_base + WO) = o_odd;   // row 2*hi+1, 16B aligned (224*4B pitch)
}

extern "C" void kernel_launch(void* const* d_in, const int* in_sizes, int n_in,
                              void* d_out, int out_size, void* d_ws, size_t ws_size,
                              hipStream_t stream) {
    const float* fm = (const float*)d_in[0];   // fp32 feature_map
    const int*   sw = (const int*)d_in[1];     // int32 switches
    float*       out = (float*)d_out;          // fp32 output

    const int total_threads = BB * CC * HH * (WW / 2);   // 12,845,056
    const int block = 256;
    const int grid  = total_threads / block;             // 50,176 exactly
    unpool_kernel<<<grid, block, 0, stream>>>(fm, sw, out);
}